// Round 7
// baseline (49.525 us; speedup 1.0000x reference)
//
#include <hip/hip_runtime.h>

#define K 5
#define N_ 8
#define C_ 256
#define H_ 64
#define W_ 64
#define HW (H_ * W_)
#define HO 128
#define WO 128
#define HOWO (HO * WO)
#define HB 8              // base rows per block
#define WB 32             // base cols per block
#define CCHUNK 64         // channels per block
#define UC 8              // channels per stage group (2 float4 slabs)
#define NGROUP (CCHUNK / UC)      // 8
#define LDS_R (HB + K - 1)        // 12
#define LDS_C (WB + K - 1)        // 36
#define POS (LDS_R * LDS_C)       // 432

typedef __attribute__((ext_vector_type(2))) float f2;

// (256,2): allow up to 256 VGPR so the 100 f2 mask values stay RESIDENT in
// registers. Grid is exactly 2 blocks/CU (512 blocks), both resident at
// 8 waves/CU, so the occupancy cap costs nothing and there is no tail.
__global__ __launch_bounds__(256, 2)
void carafe_quad_kernel(const float* __restrict__ feat,
                        const float* __restrict__ mask,
                        float* __restrict__ out) {
    const int wt = blockIdx.x;       // 0..1
    const int ht = blockIdx.y;       // 0..7
    const int zc = blockIdx.z;       // 0..31  (n*4 + chunk)
    const int n  = zc >> 2;
    const int c0 = (zc & 3) * CCHUNK;
    const int h0 = ht * HB;
    const int w0 = wt * WB;

    const int tid = threadIdx.x;
    const int r   = tid >> 5;        // 0..7  base row in tile
    const int c   = tid & 31;        // 0..31 base col in tile
    const int hb  = h0 + r;
    const int wb  = w0 + c;

    // Channel-invariant masks for this thread's 2x2 output quad, packed f2
    // over b. Loaded ONCE, then reused across all 64 channels.
    f2 m0[K * K], m1[K * K];
    {
        const f2* mb = (const f2*)(mask + (size_t)n * (K * K) * HOWO
                                        + (size_t)(2 * hb) * WO + 2 * wb);
        #pragma unroll
        for (int i = 0; i < K * K; ++i) {
            m0[i] = mb[(size_t)i * (HOWO / 2)];            // a = 0
            m1[i] = mb[(size_t)i * (HOWO / 2) + WO / 2];   // a = 1
        }
    }

    // Staging geometry: thread covers halo pos tid and tid+256 (if < POS).
    int off0, off1;
    bool v0, v1, has1;
    {
        int p  = tid;
        int rr = p / LDS_C, cc = p - rr * LDS_C;
        int hs = h0 - 2 + rr, ws = w0 - 2 + cc;
        v0   = (hs >= 0 && hs < H_ && ws >= 0 && ws < W_);
        off0 = hs * W_ + ws;
    }
    has1 = (tid + 256) < POS;
    {
        int p  = tid + 256;
        int rr = p / LDS_C, cc = p - rr * LDS_C;
        int hs = h0 - 2 + rr, ws = w0 - 2 + cc;
        v1   = has1 && (hs >= 0 && hs < H_ && ws >= 0 && ws < W_);
        off1 = hs * W_ + ws;
    }

    // Channel-interleaved halo tile: [buf][slab of 4ch][pos] as float4.
    __shared__ float4 lds[2][2][POS];   // 27648 B

    const float* fbase = feat + (size_t)n * C_ * HW;
    float*       obase = out  + (size_t)n * C_ * HOWO
                              + (size_t)(2 * hb) * WO + 2 * wb;

    float s0[UC], s1[UC];
    auto stage_load = [&](int cbase) {
        const float* fp = fbase + (size_t)cbase * HW;
        #pragma unroll
        for (int u = 0; u < UC; ++u) s0[u] = v0 ? fp[u * HW + off0] : 0.f;
        #pragma unroll
        for (int u = 0; u < UC; ++u) s1[u] = v1 ? fp[u * HW + off1] : 0.f;
    };
    auto stage_write = [&](int buf) {
        lds[buf][0][tid] = make_float4(s0[0], s0[1], s0[2], s0[3]);
        lds[buf][1][tid] = make_float4(s0[4], s0[5], s0[6], s0[7]);
        if (has1) {
            lds[buf][0][tid + 256] = make_float4(s1[0], s1[1], s1[2], s1[3]);
            lds[buf][1][tid + 256] = make_float4(s1[4], s1[5], s1[6], s1[7]);
        }
    };

    stage_load(c0);
    stage_write(0);
    __syncthreads();

    const int rbase = r * LDS_C + c;    // tap (0,0) halo position

    for (int g = 0; g < NGROUP; ++g) {
        const int buf = g & 1;

        // T14: issue next group's global loads before compute.
        if (g + 1 < NGROUP) stage_load(c0 + (g + 1) * UC);

        #pragma unroll
        for (int s = 0; s < 2; ++s) {
            const float4* Ls = &lds[buf][s][rbase];
            f2 a0[4], a1[4];
            #pragma unroll
            for (int u = 0; u < 4; ++u) { a0[u] = (f2)0.f; a1[u] = (f2)0.f; }
            #pragma unroll
            for (int ki = 0; ki < K; ++ki) {
                #pragma unroll
                for (int kj = 0; kj < K; ++kj) {
                    float4 f  = Ls[ki * LDS_C + kj];   // 1 ds_read_b128 -> 16 FMA
                    f2 w0m = m0[ki * K + kj];
                    f2 w1m = m1[ki * K + kj];
                    a0[0] += f.x * w0m;  a1[0] += f.x * w1m;
                    a0[1] += f.y * w0m;  a1[1] += f.y * w1m;
                    a0[2] += f.z * w0m;  a1[2] += f.z * w1m;
                    a0[3] += f.w * w0m;  a1[3] += f.w * w1m;
                }
            }
            #pragma unroll
            for (int u = 0; u < 4; ++u) {
                f2* op = (f2*)(obase + (size_t)(c0 + g * UC + s * 4 + u) * HOWO);
                __builtin_nontemporal_store(a0[u], op);            // row 2hb
                __builtin_nontemporal_store(a1[u], op + WO / 2);   // row 2hb+1
            }
        }

        if (g + 1 < NGROUP) {
            stage_write(buf ^ 1);
            __syncthreads();
        }
    }
}

extern "C" void kernel_launch(void* const* d_in, const int* in_sizes, int n_in,
                              void* d_out, int out_size, void* d_ws, size_t ws_size,
                              hipStream_t stream) {
    const float* feat = (const float*)d_in[0];
    const float* mask = (const float*)d_in[1];
    float* out = (float*)d_out;

    dim3 grid(W_ / WB, H_ / HB, N_ * (C_ / CCHUNK));  // (2, 8, 32) = 512 blocks
    dim3 block(256);
    carafe_quad_kernel<<<grid, block, 0, stream>>>(feat, mask, out);
}

// Round 8
// 47.964 us; speedup vs baseline: 1.0325x; 1.0325x over previous
//
#include <hip/hip_runtime.h>

#define K 5
#define N_ 8
#define C_ 256
#define H_ 64
#define W_ 64
#define HW (H_ * W_)
#define HO 128
#define WO 128
#define HOWO (HO * WO)
#define HB 8              // base rows per block
#define WB 32             // base cols per block
#define CCHUNK 16         // channels per block
#define UC 8              // channels per stage group (2 float4 slabs)
#define NGROUP (CCHUNK / UC)      // 2
#define LDS_R (HB + K - 1)        // 12
#define LDS_C (WB + K - 1)        // 36
#define POS (LDS_R * LDS_C)       // 432

typedef __attribute__((ext_vector_type(2))) float f2;

__global__ __launch_bounds__(256)
void carafe_quad_kernel(const float* __restrict__ feat,
                        const float* __restrict__ mask,
                        float* __restrict__ out) {
    const int wt = blockIdx.x;       // 0..1
    const int ht = blockIdx.y;       // 0..7
    const int zc = blockIdx.z;       // 0..127  (n*16 + chunk)
    const int n  = zc >> 4;
    const int c0 = (zc & 15) * CCHUNK;
    const int h0 = ht * HB;
    const int w0 = wt * WB;

    const int tid = threadIdx.x;
    const int r   = tid >> 5;        // 0..7  base row in tile
    const int c   = tid & 31;        // 0..31 base col in tile
    const int hb  = h0 + r;
    const int wb  = w0 + c;

    // Channel-invariant masks for this thread's 2x2 output quad (f2 over b).
    f2 m0[K * K], m1[K * K];
    {
        const f2* mb = (const f2*)(mask + (size_t)n * (K * K) * HOWO
                                        + (size_t)(2 * hb) * WO + 2 * wb);
        #pragma unroll
        for (int i = 0; i < K * K; ++i) {
            m0[i] = mb[(size_t)i * (HOWO / 2)];            // a = 0
            m1[i] = mb[(size_t)i * (HOWO / 2) + WO / 2];   // a = 1
        }
    }

    // Staging geometry: thread covers halo pos tid and tid+256 (if < POS).
    int off0, off1;
    bool v0, v1, has1;
    {
        int p  = tid;
        int rr = p / LDS_C, cc = p - rr * LDS_C;
        int hs = h0 - 2 + rr, ws = w0 - 2 + cc;
        v0   = (hs >= 0 && hs < H_ && ws >= 0 && ws < W_);
        off0 = hs * W_ + ws;
    }
    has1 = (tid + 256) < POS;
    {
        int p  = tid + 256;
        int rr = p / LDS_C, cc = p - rr * LDS_C;
        int hs = h0 - 2 + rr, ws = w0 - 2 + cc;
        v1   = has1 && (hs >= 0 && hs < H_ && ws >= 0 && ws < W_);
        off1 = hs * W_ + ws;
    }

    // Channel-interleaved halo tile: [buf][slab of 4ch][pos] as float4.
    __shared__ float4 lds[2][2][POS];   // 27648 B -> ~5 blocks/CU

    const float* fbase = feat + (size_t)n * C_ * HW;
    float*       obase = out  + (size_t)n * C_ * HOWO
                              + (size_t)(2 * hb) * WO + 2 * wb;

    float s0[UC], s1[UC];
    auto stage_load = [&](int cbase) {
        const float* fp = fbase + (size_t)cbase * HW;
        #pragma unroll
        for (int u = 0; u < UC; ++u) s0[u] = v0 ? fp[u * HW + off0] : 0.f;
        #pragma unroll
        for (int u = 0; u < UC; ++u) s1[u] = v1 ? fp[u * HW + off1] : 0.f;
    };
    auto stage_write = [&](int buf) {
        lds[buf][0][tid] = make_float4(s0[0], s0[1], s0[2], s0[3]);
        lds[buf][1][tid] = make_float4(s0[4], s0[5], s0[6], s0[7]);
        if (has1) {
            lds[buf][0][tid + 256] = make_float4(s1[0], s1[1], s1[2], s1[3]);
            lds[buf][1][tid + 256] = make_float4(s1[4], s1[5], s1[6], s1[7]);
        }
    };

    stage_load(c0);
    stage_write(0);
    __syncthreads();

    const int rbase = r * LDS_C + c;    // tap (0,0) halo position

    for (int g = 0; g < NGROUP; ++g) {
        const int buf = g & 1;

        // T14: issue next group's global loads before compute.
        if (g + 1 < NGROUP) stage_load(c0 + (g + 1) * UC);

        #pragma unroll
        for (int s = 0; s < 2; ++s) {
            const float4* Ls = &lds[buf][s][rbase];
            f2 a0[4], a1[4];
            #pragma unroll
            for (int u = 0; u < 4; ++u) { a0[u] = (f2)0.f; a1[u] = (f2)0.f; }
            #pragma unroll
            for (int ki = 0; ki < K; ++ki) {
                #pragma unroll
                for (int kj = 0; kj < K; ++kj) {
                    float4 f  = Ls[ki * LDS_C + kj];   // 1 ds_read_b128 -> 16 FMA
                    f2 w0m = m0[ki * K + kj];
                    f2 w1m = m1[ki * K + kj];
                    a0[0] += f.x * w0m;  a1[0] += f.x * w1m;
                    a0[1] += f.y * w0m;  a1[1] += f.y * w1m;
                    a0[2] += f.z * w0m;  a1[2] += f.z * w1m;
                    a0[3] += f.w * w0m;  a1[3] += f.w * w1m;
                }
            }
            // Plain (cached) stores: let L2 write-combine the stream.
            #pragma unroll
            for (int u = 0; u < 4; ++u) {
                f2* op = (f2*)(obase + (size_t)(c0 + g * UC + s * 4 + u) * HOWO);
                op[0]      = a0[u];   // row 2hb
                op[WO / 2] = a1[u];   // row 2hb+1
            }
        }

        if (g + 1 < NGROUP) {
            stage_write(buf ^ 1);
            __syncthreads();
        }
    }
}

extern "C" void kernel_launch(void* const* d_in, const int* in_sizes, int n_in,
                              void* d_out, int out_size, void* d_ws, size_t ws_size,
                              hipStream_t stream) {
    const float* feat = (const float*)d_in[0];
    const float* mask = (const float*)d_in[1];
    float* out = (float*)d_out;

    dim3 grid(W_ / WB, H_ / HB, N_ * (C_ / CCHUNK));  // (2, 8, 128) = 2048 blocks
    dim3 block(256);
    carafe_quad_kernel<<<grid, block, 0, stream>>>(feat, mask, out);
}

// Round 9
// 42.766 us; speedup vs baseline: 1.1580x; 1.1216x over previous
//
#include <hip/hip_runtime.h>

#define K 5
#define N_ 8
#define C_ 256
#define H_ 64
#define W_ 64
#define HW (H_ * W_)
#define HO 128
#define WO 128
#define HOWO (HO * WO)
#define HB 4              // base rows per block (full width)
#define CCHUNK 32         // channels per block
#define UC 8              // channels per stage group (2 float4 slabs)
#define NGROUP (CCHUNK / UC)      // 4
#define LDS_R (HB + K - 1)        // 8 halo rows
#define LDS_C 68                  // 64 cols + 2 pad each side (zero-filled)
#define POS (LDS_R * LDS_C)       // 544

typedef __attribute__((ext_vector_type(2))) float f2;

__global__ __launch_bounds__(256)
void carafe_row_kernel(const float* __restrict__ feat,
                       const float* __restrict__ mask,
                       float* __restrict__ out) {
    const int ht = blockIdx.x;       // 0..15
    const int zc = blockIdx.y;       // 0..63 (n*8 + chunk)
    const int n  = zc >> 3;
    const int c0 = (zc & 7) * CCHUNK;
    const int h0 = ht * HB;

    const int tid = threadIdx.x;
    const int r   = tid >> 6;        // 0..3  base row (one wave = one row)
    const int c   = tid & 63;        // 0..63 base col (full width)
    const int hb  = h0 + r;

    // Channel-invariant masks for this thread's 2x2 output quad (f2 over b).
    f2 m0[K * K], m1[K * K];
    {
        const f2* mb = (const f2*)(mask + (size_t)n * (K * K) * HOWO
                                        + (size_t)(2 * hb) * WO + 2 * c);
        #pragma unroll
        for (int i = 0; i < K * K; ++i) {
            m0[i] = mb[(size_t)i * (HOWO / 2)];            // a = 0
            m1[i] = mb[(size_t)i * (HOWO / 2) + WO / 2];   // a = 1
        }
    }

    // Staging geometry: halo positions tid, tid+256, tid+512 (if < POS).
    // Halo: rows h0-2 .. h0+5, cols -2..65 (pad cols zero-filled).
    int off[3]; bool val[3];
    #pragma unroll
    for (int i = 0; i < 3; ++i) {
        int p  = tid + i * 256;
        int rr = p / LDS_C, cc = p - rr * LDS_C;
        int hs = h0 - 2 + rr;
        int ws = cc - 2;
        val[i] = (p < POS) && (hs >= 0) && (hs < H_) && (ws >= 0) && (ws < W_);
        off[i] = hs * W_ + ws;
    }

    // Channel-interleaved halo tile: [buf][slab of 4ch][pos] float4. 34816 B.
    __shared__ float4 lds[2][2][POS];

    const float* fbase = feat + (size_t)n * C_ * HW;
    float*       obase = out  + (size_t)n * C_ * HOWO
                              + (size_t)(2 * hb) * WO + 2 * c;

    float s[3][UC];
    auto stage_load = [&](int cbase) {
        const float* fp = fbase + (size_t)cbase * HW;
        #pragma unroll
        for (int i = 0; i < 3; ++i)
            #pragma unroll
            for (int u = 0; u < UC; ++u)
                s[i][u] = val[i] ? fp[u * HW + off[i]] : 0.f;
    };
    auto stage_write = [&](int buf) {
        #pragma unroll
        for (int i = 0; i < 3; ++i) {
            int p = tid + i * 256;
            if (p < POS) {
                lds[buf][0][p] = make_float4(s[i][0], s[i][1], s[i][2], s[i][3]);
                lds[buf][1][p] = make_float4(s[i][4], s[i][5], s[i][6], s[i][7]);
            }
        }
    };

    stage_load(c0);
    stage_write(0);
    __syncthreads();

    // Tap (ki,kj) for base (r,c): halo row r+ki, padded col c+kj.
    const int rbase = r * LDS_C + c;

    for (int g = 0; g < NGROUP; ++g) {
        const int buf = g & 1;

        // T14: issue next group's global loads before compute.
        if (g + 1 < NGROUP) stage_load(c0 + (g + 1) * UC);

        #pragma unroll
        for (int ss = 0; ss < 2; ++ss) {
            const float4* Ls = &lds[buf][ss][rbase];
            f2 a0[4], a1[4];
            #pragma unroll
            for (int u = 0; u < 4; ++u) { a0[u] = (f2)0.f; a1[u] = (f2)0.f; }
            #pragma unroll
            for (int ki = 0; ki < K; ++ki) {
                #pragma unroll
                for (int kj = 0; kj < K; ++kj) {
                    float4 f  = Ls[ki * LDS_C + kj];   // 1 ds_read_b128 -> 16 FMA
                    f2 w0m = m0[ki * K + kj];
                    f2 w1m = m1[ki * K + kj];
                    a0[0] += f.x * w0m;  a1[0] += f.x * w1m;
                    a0[1] += f.y * w0m;  a1[1] += f.y * w1m;
                    a0[2] += f.z * w0m;  a1[2] += f.z * w1m;
                    a0[3] += f.w * w0m;  a1[3] += f.w * w1m;
                }
            }
            // One wave = one base row: each store inst covers a full,
            // aligned 512B output row; block writes 8 consecutive rows
            // (4KB contiguous) per channel.
            #pragma unroll
            for (int u = 0; u < 4; ++u) {
                f2* op = (f2*)(obase + (size_t)(c0 + g * UC + ss * 4 + u) * HOWO);
                __builtin_nontemporal_store(a0[u], op);            // row 2hb
                __builtin_nontemporal_store(a1[u], op + WO / 2);   // row 2hb+1
            }
        }

        if (g + 1 < NGROUP) {
            stage_write(buf ^ 1);
            __syncthreads();
        }
    }
}

extern "C" void kernel_launch(void* const* d_in, const int* in_sizes, int n_in,
                              void* d_out, int out_size, void* d_ws, size_t ws_size,
                              hipStream_t stream) {
    const float* feat = (const float*)d_in[0];
    const float* mask = (const float*)d_in[1];
    float* out = (float*)d_out;

    dim3 grid(H_ / HB, N_ * (C_ / CCHUNK));  // (16, 64) = 1024 blocks
    dim3 block(256);
    carafe_row_kernel<<<grid, block, 0, stream>>>(feat, mask, out);
}